// Round 1
// 983.692 us; speedup vs baseline: 1.0493x; 1.0493x over previous
//
#include <hip/hip_runtime.h>

#define B_    128
#define NPOS  64
#define DIN   1024
#define HH    16
#define DH    64
#define E_    1024

typedef __bf16 bf16x8 __attribute__((ext_vector_type(8)));
typedef float  f32x4  __attribute__((ext_vector_type(4)));

union F4 { float4 v; float f[4]; };

__device__ __forceinline__ unsigned int pk2bf(float a, float b) {
    unsigned int ua = __float_as_uint(a);
    unsigned int ub = __float_as_uint(b);
    ua = (ua + 0x7fffu + ((ua >> 16) & 1u)) >> 16;
    ub = (ub + 0x7fffu + ((ub >> 16) & 1u)) >> 16;
    return ua | (ub << 16);
}
__device__ __forceinline__ unsigned short f2bf(float a) {
    unsigned int u = __float_as_uint(a);
    u = (u + 0x7fffu + ((u >> 16) & 1u)) >> 16;
    return (unsigned short)u;
}
__device__ __forceinline__ float bf2f(unsigned int u) {
    return __uint_as_float(u << 16);
}

// ---------------- Kernel 1: grouped projections (q,k,v) ----------------
// per block: C[128 x 128] = A[128 x 1024] * B[1024 x 128] for one position n
// Changes vs prev: (1) Bs XOR-swizzle keyed on row>>2 kills the 16-way
// transpose-write bank conflict; (2) next tile's A+B globals are prefetched
// into registers before the MFMA phase so HBM loads stay in flight across
// MFMA + barrier; (3) launch_bounds(256,3) gives the allocator room for the
// ~145 VGPR prefetch live range (no spill) at 12 waves/CU.
__global__ __launch_bounds__(256, 3) void proj_kernel(
    const float* __restrict__ qin, const float* __restrict__ kin, const float* __restrict__ vin,
    const float* __restrict__ wq,  const float* __restrict__ wk,  const float* __restrict__ wv,
    unsigned short* __restrict__ qp, unsigned short* __restrict__ kp, unsigned short* __restrict__ vp) {
    const int e0 = blockIdx.x * 128;
    const int n  = blockIdx.y;
    const int z  = blockIdx.z;
    const float* in = (z == 0) ? qin : (z == 1) ? kin : vin;
    const float* w  = (z == 0) ? wq  : (z == 1) ? wk  : wv;
    unsigned short* outp = (z == 0) ? qp : (z == 1) ? kp : vp;

    __shared__ __attribute__((aligned(16))) unsigned short As[128 * 72]; // [m][k]
    __shared__ __attribute__((aligned(16))) unsigned short Bs[128 * 72]; // [e][k] xor-swizzled

    const int t = threadIdx.x;
    const int lane = t & 63, wave = t >> 6;
    const int wm = wave >> 1, wn = wave & 1;

    f32x4 acc[4][4];
#pragma unroll
    for (int i = 0; i < 4; i++)
#pragma unroll
        for (int j = 0; j < 4; j++) acc[i][j] = (f32x4){0.f, 0.f, 0.f, 0.f};

    const float* inA = in + n * DIN;                       // + m*(NPOS*DIN) + k
    const float* wB  = w + (size_t)n * DIN * E_ + e0;      // + k*E_ + e

    const int afr = t & 15, ar0 = t >> 4;                  // A staging: 16 f4/row
    const int beb = t & 31, bkq = t >> 5;                  // B staging
    const int bS  = (beb & 7) << 4;                        // Bs swizzle key (row>>2 == beb)

    F4 rA[8];
    F4 rB[2][4];

    // prefetch tile kb=0 into registers
#pragma unroll
    for (int p = 0; p < 8; p++)
        rA[p].v = *(const float4*)(inA + (size_t)(ar0 + p * 16) * (NPOS * DIN) + afr * 4);
#pragma unroll
    for (int p = 0; p < 2; p++) {
        const float* src = wB + (size_t)((bkq + p * 8) * 4) * E_ + beb * 4;
#pragma unroll
        for (int x = 0; x < 4; x++) rB[p][x].v = *(const float4*)(src + (size_t)x * E_);
    }

    for (int kb = 0; kb < DIN; kb += 64) {
        // ---- convert + store staged tile to LDS (waits on in-flight loads) ----
#pragma unroll
        for (int p = 0; p < 8; p++) {
            int row = ar0 + p * 16;
            uint2 pk; pk.x = pk2bf(rA[p].f[0], rA[p].f[1]); pk.y = pk2bf(rA[p].f[2], rA[p].f[3]);
            *(uint2*)&As[row * 72 + afr * 4] = pk;
        }
#pragma unroll
        for (int p = 0; p < 2; p++) {
            int kby = ((bkq + p * 8) * 8) ^ bS;            // byte offset 2k, swizzled
#pragma unroll
            for (int x = 0; x < 4; x++) {
                uint2 pk; pk.x = pk2bf(rB[p][0].f[x], rB[p][1].f[x]);
                pk.y = pk2bf(rB[p][2].f[x], rB[p][3].f[x]);
                *(uint2*)((char*)Bs + (beb * 4 + x) * 144 + kby) = pk;
            }
        }
        __syncthreads();
        // ---- prefetch next tile into regs: overlaps the MFMA phase below ----
        if (kb + 64 < DIN) {
            const int kn = kb + 64;
#pragma unroll
            for (int p = 0; p < 8; p++)
                rA[p].v = *(const float4*)(inA + (size_t)(ar0 + p * 16) * (NPOS * DIN) + kn + afr * 4);
#pragma unroll
            for (int p = 0; p < 2; p++) {
                const float* src = wB + (size_t)(kn + (bkq + p * 8) * 4) * E_ + beb * 4;
#pragma unroll
                for (int x = 0; x < 4; x++) rB[p][x].v = *(const float4*)(src + (size_t)x * E_);
            }
        }
        // ---- MFMA on current tile ----
#pragma unroll
        for (int ks = 0; ks < 64; ks += 32) {
            bf16x8 a[4], b[4];
            const int koff = ks + (lane >> 4) * 8;
#pragma unroll
            for (int i = 0; i < 4; i++)
                a[i] = *(const bf16x8*)&As[(wm * 64 + i * 16 + (lane & 15)) * 72 + koff];
#pragma unroll
            for (int j = 0; j < 4; j++) {
                int row = wn * 64 + j * 16 + (lane & 15);
                b[j] = *(const bf16x8*)((const char*)Bs + row * 144 +
                                        ((2 * koff) ^ (((row >> 2) & 7) << 4)));
            }
#pragma unroll
            for (int i = 0; i < 4; i++)
#pragma unroll
                for (int j = 0; j < 4; j++)
                    acc[i][j] = __builtin_amdgcn_mfma_f32_16x16x32_bf16(a[i], b[j], acc[i][j], 0, 0, 0);
        }
        __syncthreads();
    }
    // epilogue: C/D map col=lane&15, row=(lane>>4)*4+r  -> bf16 store
    const int col_l = lane & 15, rq = lane >> 4;
#pragma unroll
    for (int i = 0; i < 4; i++)
#pragma unroll
        for (int j = 0; j < 4; j++) {
            int e = e0 + wn * 64 + j * 16 + col_l;
#pragma unroll
            for (int r = 0; r < 4; r++) {
                int m = wm * 64 + i * 16 + rq * 4 + r;
                outp[(size_t)m * (NPOS * E_) + n * E_ + e] = f2bf(acc[i][j][r]);
            }
        }
}

// ---------------- Kernel 2: attention per (b,h) ----------------
__global__ __launch_bounds__(256) void attn_kernel(
    const unsigned short* __restrict__ qp, const unsigned short* __restrict__ kp,
    const unsigned short* __restrict__ vp,
    float* __restrict__ attn_out,            // [B][H][64][64] fp32
    unsigned short* __restrict__ out_ws) {   // bf16 [B][64][H*DH]
    const int bid = blockIdx.x;
    const int b = bid >> 4, h = bid & 15;
    __shared__ __attribute__((aligned(16))) float qs[64 * 68];   // q tile; reused for V
    __shared__ __attribute__((aligned(16))) float kt[64 * 68];   // K transposed [d][j]
    __shared__ __attribute__((aligned(16))) float sc[64 * 68];   // scores / attn
    const int t = threadIdx.x;
    const size_t base = (size_t)b * 64 * E_ + h * DH;

    // stage q and k^T
#pragma unroll
    for (int p = 0; p < 4; p++) {
        int idx = p * 1024 + t * 4;
        int r = idx >> 6, c = idx & 63;
        uint2 q2 = *(const uint2*)(qp + base + r * E_ + c);
        float4 qv = { bf2f(q2.x & 0xffffu), bf2f(q2.x >> 16), bf2f(q2.y & 0xffffu), bf2f(q2.y >> 16) };
        *(float4*)&qs[r * 68 + c] = qv;
        uint2 k2 = *(const uint2*)(kp + base + r * E_ + c);
        kt[(c + 0) * 68 + r] = bf2f(k2.x & 0xffffu);
        kt[(c + 1) * 68 + r] = bf2f(k2.x >> 16);
        kt[(c + 2) * 68 + r] = bf2f(k2.y & 0xffffu);
        kt[(c + 3) * 68 + r] = bf2f(k2.y >> 16);
    }
    __syncthreads();
    const int ti = t >> 4, tj = t & 15;
    const int i0 = ti * 4, j0 = tj * 4;
    float s[4][4] = {};
    for (int k4 = 0; k4 < 64; k4 += 4) {
        F4 qv[4], kv[4];
#pragma unroll
        for (int r = 0; r < 4; r++) qv[r].v = *(const float4*)&qs[(i0 + r) * 68 + k4];
#pragma unroll
        for (int kk = 0; kk < 4; kk++) kv[kk].v = *(const float4*)&kt[(k4 + kk) * 68 + j0];
#pragma unroll
        for (int r = 0; r < 4; r++)
#pragma unroll
            for (int c = 0; c < 4; c++)
#pragma unroll
                for (int kk = 0; kk < 4; kk++)
                    s[r][c] += qv[r].f[kk] * kv[kk].f[c];
    }
#pragma unroll
    for (int r = 0; r < 4; r++)
#pragma unroll
        for (int c = 0; c < 4; c++)
            sc[(i0 + r) * 68 + j0 + c] = s[r][c] * 0.125f;   // 1/sqrt(64)
    __syncthreads();
    // stage V into qs (q no longer needed)
#pragma unroll
    for (int p = 0; p < 4; p++) {
        int idx = p * 1024 + t * 4;
        int r = idx >> 6, c = idx & 63;
        uint2 v2 = *(const uint2*)(vp + base + r * E_ + c);
        float4 vv = { bf2f(v2.x & 0xffffu), bf2f(v2.x >> 16), bf2f(v2.y & 0xffffu), bf2f(v2.y >> 16) };
        *(float4*)&qs[r * 68 + c] = vv;
    }
    // softmax per row
    if (t < 64) {
        float m = -1e30f;
        for (int j = 0; j < 64; j++) m = fmaxf(m, sc[t * 68 + j]);
        float sum = 0.f;
        for (int j = 0; j < 64; j++) {
            float e = __expf(sc[t * 68 + j] - m);
            sc[t * 68 + j] = e; sum += e;
        }
        float inv = 1.f / sum;
        for (int j = 0; j < 64; j++) sc[t * 68 + j] *= inv;
    }
    __syncthreads();
    // write attn (output 1)
    float* abase = attn_out + (size_t)bid * 4096;
#pragma unroll
    for (int p = 0; p < 4; p++) {
        int idx = p * 1024 + t * 4;
        int r = idx >> 6, c = idx & 63;
        float4 av = { sc[r * 68 + c], sc[r * 68 + c + 1], sc[r * 68 + c + 2], sc[r * 68 + c + 3] };
        *(float4*)(abase + idx) = av;
    }
    // PV
    float o[4][4] = {};
    for (int j4 = 0; j4 < 64; j4 += 4) {
        F4 av[4], vv[4];
#pragma unroll
        for (int r = 0; r < 4; r++) av[r].v = *(const float4*)&sc[(i0 + r) * 68 + j4];
#pragma unroll
        for (int jj = 0; jj < 4; jj++) vv[jj].v = *(const float4*)&qs[(j4 + jj) * 68 + j0];
#pragma unroll
        for (int r = 0; r < 4; r++)
#pragma unroll
            for (int c = 0; c < 4; c++)
#pragma unroll
                for (int jj = 0; jj < 4; jj++)
                    o[r][c] += av[r].f[jj] * vv[jj].f[c];
    }
#pragma unroll
    for (int r = 0; r < 4; r++) {
        uint2 pk; pk.x = pk2bf(o[r][0], o[r][1]); pk.y = pk2bf(o[r][2], o[r][3]);
        *(uint2*)(out_ws + (size_t)(b * 64 + i0 + r) * E_ + h * DH + j0) = pk;
    }
}

// ---------------- Kernel 3: fused fc + gate + activation ----------------
// C_fc[m,n] = sum_k out[m,k]*fc_w[n,k] ; C_g likewise ; out = sigmoid(g+gb)*tanh(f+fb)
__global__ __launch_bounds__(256, 2) void fcgate_kernel(
    const unsigned short* __restrict__ a,   // bf16 [8192][1024]
    const float* __restrict__ fcw, const float* __restrict__ fcb,
    const float* __restrict__ gw,  const float* __restrict__ gb,
    float* __restrict__ outp) {             // fp32 [8192][1024]
    const int n0 = blockIdx.x * 128;
    const int m0 = blockIdx.y * 128;
    __shared__ __attribute__((aligned(16))) unsigned short As[128 * 72];
    __shared__ __attribute__((aligned(16))) unsigned short Bf[128 * 72];
    __shared__ __attribute__((aligned(16))) unsigned short Bg[128 * 72];
    const int t = threadIdx.x;
    const int lane = t & 63, wave = t >> 6;
    const int wm = wave >> 1, wn = wave & 1;

    f32x4 accf[4][4], accg[4][4];
#pragma unroll
    for (int i = 0; i < 4; i++)
#pragma unroll
        for (int j = 0; j < 4; j++) {
            accf[i][j] = (f32x4){0.f, 0.f, 0.f, 0.f};
            accg[i][j] = (f32x4){0.f, 0.f, 0.f, 0.f};
        }

    const int afr = t & 7,  ar0 = t >> 3;   // A: 8 x 16B chunks per row
    const int bfr = t & 15, br0 = t >> 4;   // B: 16 x float4 per row

    for (int kb = 0; kb < 1024; kb += 64) {
#pragma unroll
        for (int p = 0; p < 4; p++) {
            int row = ar0 + p * 32;
            *(uint4*)&As[row * 72 + afr * 8] =
                *(const uint4*)(a + (size_t)(m0 + row) * 1024 + kb + afr * 8);
        }
#pragma unroll
        for (int p = 0; p < 8; p++) {
            int row = br0 + p * 16;
            F4 cf; cf.v = *(const float4*)(fcw + (size_t)(n0 + row) * 1024 + kb + bfr * 4);
            uint2 pkf; pkf.x = pk2bf(cf.f[0], cf.f[1]); pkf.y = pk2bf(cf.f[2], cf.f[3]);
            *(uint2*)&Bf[row * 72 + bfr * 4] = pkf;
            F4 cg; cg.v = *(const float4*)(gw + (size_t)(n0 + row) * 1024 + kb + bfr * 4);
            uint2 pkg; pkg.x = pk2bf(cg.f[0], cg.f[1]); pkg.y = pk2bf(cg.f[2], cg.f[3]);
            *(uint2*)&Bg[row * 72 + bfr * 4] = pkg;
        }
        __syncthreads();
#pragma unroll
        for (int ks = 0; ks < 64; ks += 32) {
            bf16x8 av[4], bfv[4], bgv[4];
            const int koff = ks + (lane >> 4) * 8;
#pragma unroll
            for (int i = 0; i < 4; i++)
                av[i] = *(const bf16x8*)&As[(wm * 64 + i * 16 + (lane & 15)) * 72 + koff];
#pragma unroll
            for (int j = 0; j < 4; j++) {
                bfv[j] = *(const bf16x8*)&Bf[(wn * 64 + j * 16 + (lane & 15)) * 72 + koff];
                bgv[j] = *(const bf16x8*)&Bg[(wn * 64 + j * 16 + (lane & 15)) * 72 + koff];
            }
#pragma unroll
            for (int i = 0; i < 4; i++)
#pragma unroll
                for (int j = 0; j < 4; j++) {
                    accf[i][j] = __builtin_amdgcn_mfma_f32_16x16x32_bf16(av[i], bfv[j], accf[i][j], 0, 0, 0);
                    accg[i][j] = __builtin_amdgcn_mfma_f32_16x16x32_bf16(av[i], bgv[j], accg[i][j], 0, 0, 0);
                }
        }
        __syncthreads();
    }
    const int col_l = lane & 15, rq = lane >> 4;
#pragma unroll
    for (int i = 0; i < 4; i++)
#pragma unroll
        for (int j = 0; j < 4; j++) {
            int col = n0 + wn * 64 + j * 16 + col_l;
            float bfb = fcb[col], bgb = gb[col];
#pragma unroll
            for (int r = 0; r < 4; r++) {
                int m = m0 + wm * 64 + i * 16 + rq * 4 + r;
                float f = accf[i][j][r] + bfb;
                float g = accg[i][j][r] + bgb;
                float ef = __expf(2.f * f);
                float th = (ef - 1.f) / (ef + 1.f);      // tanh(f)
                float sg = 1.f / (1.f + __expf(-g));     // sigmoid(g)
                outp[(size_t)m * 1024 + col] = sg * th;
            }
        }
}

extern "C" void kernel_launch(void* const* d_in, const int* in_sizes, int n_in,
                              void* d_out, int out_size, void* d_ws, size_t ws_size,
                              hipStream_t stream) {
    const float* q      = (const float*)d_in[0];
    const float* k      = (const float*)d_in[1];
    const float* v      = (const float*)d_in[2];
    const float* w_q    = (const float*)d_in[3];
    const float* w_k    = (const float*)d_in[4];
    const float* w_v    = (const float*)d_in[5];
    const float* fc_w   = (const float*)d_in[6];
    const float* fc_b   = (const float*)d_in[7];
    const float* gate_w = (const float*)d_in[8];
    const float* gate_b = (const float*)d_in[9];

    float* out  = (float*)d_out;              // [128*64][1024]
    float* attn = out + 8388608;              // [128][16][64][64]

    unsigned short* qp  = (unsigned short*)d_ws;   // bf16 [128][64][1024] each
    unsigned short* kp  = qp + 8388608;
    unsigned short* vp  = kp + 8388608;
    unsigned short* ows = vp + 8388608;            // bf16 [8192][1024]

    dim3 blk(256);
    proj_kernel<<<dim3(8, 64, 3), blk, 0, stream>>>(q, k, v, w_q, w_k, w_v, qp, kp, vp);
    attn_kernel<<<dim3(2048), blk, 0, stream>>>(qp, kp, vp, attn, ows);
    fcgate_kernel<<<dim3(8, 64), blk, 0, stream>>>(ows, fc_w, fc_b, gate_w, gate_b, out);
}

// Round 3
// 967.316 us; speedup vs baseline: 1.0670x; 1.0169x over previous
//
#include <hip/hip_runtime.h>

#define B_    128
#define NPOS  64
#define DIN   1024
#define HH    16
#define DH    64
#define E_    1024

typedef __bf16 bf16x8 __attribute__((ext_vector_type(8)));
typedef float  f32x4  __attribute__((ext_vector_type(4)));

union F4 { float4 v; float f[4]; };

__device__ __forceinline__ unsigned int pk2bf(float a, float b) {
    unsigned int ua = __float_as_uint(a);
    unsigned int ub = __float_as_uint(b);
    ua = (ua + 0x7fffu + ((ua >> 16) & 1u)) >> 16;
    ub = (ub + 0x7fffu + ((ub >> 16) & 1u)) >> 16;
    return ua | (ub << 16);
}
__device__ __forceinline__ unsigned short f2bf(float a) {
    unsigned int u = __float_as_uint(a);
    u = (u + 0x7fffu + ((u >> 16) & 1u)) >> 16;
    return (unsigned short)u;
}
__device__ __forceinline__ float bf2f(unsigned int u) {
    return __uint_as_float(u << 16);
}

// ---------------- Kernel 1: grouped projections (q,k,v) ----------------
// per block: C[128 x 128] = A[128 x 1024] * B[1024 x 128] for one position n
// Swizzle key for Bs is ((row>>3)&7)<<4: combined with the row-stride's
// (row>>2 & 1) bank bit this spreads each Bs transpose-store uniformly over
// all 16 bank-pairs (old (beb&7) key overlapped the stride bit -> 4-way).
__global__ __launch_bounds__(256, 3) void proj_kernel(
    const float* __restrict__ qin, const float* __restrict__ kin, const float* __restrict__ vin,
    const float* __restrict__ wq,  const float* __restrict__ wk,  const float* __restrict__ wv,
    unsigned short* __restrict__ qp, unsigned short* __restrict__ kp, unsigned short* __restrict__ vp) {
    const int e0 = blockIdx.x * 128;
    const int n  = blockIdx.y;
    const int z  = blockIdx.z;
    const float* in = (z == 0) ? qin : (z == 1) ? kin : vin;
    const float* w  = (z == 0) ? wq  : (z == 1) ? wk  : wv;
    unsigned short* outp = (z == 0) ? qp : (z == 1) ? kp : vp;

    __shared__ __attribute__((aligned(16))) unsigned short As[128 * 72]; // [m][k]
    __shared__ __attribute__((aligned(16))) unsigned short Bs[128 * 72]; // [e][k] xor-swizzled

    const int t = threadIdx.x;
    const int lane = t & 63, wave = t >> 6;
    const int wm = wave >> 1, wn = wave & 1;

    f32x4 acc[4][4];
#pragma unroll
    for (int i = 0; i < 4; i++)
#pragma unroll
        for (int j = 0; j < 4; j++) acc[i][j] = (f32x4){0.f, 0.f, 0.f, 0.f};

    const float* inA = in + n * DIN;                       // + m*(NPOS*DIN) + k
    const float* wB  = w + (size_t)n * DIN * E_ + e0;      // + k*E_ + e

    const int afr = t & 15, ar0 = t >> 4;                  // A staging: 16 f4/row
    const int beb = t & 31, bkq = t >> 5;                  // B staging
    const int bS  = ((beb >> 1) & 7) << 4;                 // swizzle key = ((row>>3)&7)<<4

    F4 rA[8];
    F4 rB[2][4];

    // prefetch tile kb=0 into registers
#pragma unroll
    for (int p = 0; p < 8; p++)
        rA[p].v = *(const float4*)(inA + (size_t)(ar0 + p * 16) * (NPOS * DIN) + afr * 4);
#pragma unroll
    for (int p = 0; p < 2; p++) {
        const float* src = wB + (size_t)((bkq + p * 8) * 4) * E_ + beb * 4;
#pragma unroll
        for (int x = 0; x < 4; x++) rB[p][x].v = *(const float4*)(src + (size_t)x * E_);
    }

    for (int kb = 0; kb < DIN; kb += 64) {
        // ---- convert + store staged tile to LDS (waits on in-flight loads) ----
#pragma unroll
        for (int p = 0; p < 8; p++) {
            int row = ar0 + p * 16;
            uint2 pk; pk.x = pk2bf(rA[p].f[0], rA[p].f[1]); pk.y = pk2bf(rA[p].f[2], rA[p].f[3]);
            *(uint2*)&As[row * 72 + afr * 4] = pk;
        }
#pragma unroll
        for (int p = 0; p < 2; p++) {
            int kby = ((bkq + p * 8) * 8) ^ bS;            // byte offset 2k, swizzled
#pragma unroll
            for (int x = 0; x < 4; x++) {
                uint2 pk; pk.x = pk2bf(rB[p][0].f[x], rB[p][1].f[x]);
                pk.y = pk2bf(rB[p][2].f[x], rB[p][3].f[x]);
                *(uint2*)((char*)Bs + (beb * 4 + x) * 144 + kby) = pk;
            }
        }
        __syncthreads();
        // ---- prefetch next tile into regs: overlaps the MFMA phase below ----
        if (kb + 64 < DIN) {
            const int kn = kb + 64;
#pragma unroll
            for (int p = 0; p < 8; p++)
                rA[p].v = *(const float4*)(inA + (size_t)(ar0 + p * 16) * (NPOS * DIN) + kn + afr * 4);
#pragma unroll
            for (int p = 0; p < 2; p++) {
                const float* src = wB + (size_t)(kn + (bkq + p * 8) * 4) * E_ + beb * 4;
#pragma unroll
                for (int x = 0; x < 4; x++) rB[p][x].v = *(const float4*)(src + (size_t)x * E_);
            }
        }
        // ---- MFMA on current tile ----
#pragma unroll
        for (int ks = 0; ks < 64; ks += 32) {
            bf16x8 a[4], b[4];
            const int koff = ks + (lane >> 4) * 8;
#pragma unroll
            for (int i = 0; i < 4; i++)
                a[i] = *(const bf16x8*)&As[(wm * 64 + i * 16 + (lane & 15)) * 72 + koff];
#pragma unroll
            for (int j = 0; j < 4; j++) {
                int row = wn * 64 + j * 16 + (lane & 15);
                b[j] = *(const bf16x8*)((const char*)Bs + row * 144 +
                                        ((2 * koff) ^ (((row >> 3) & 7) << 4)));
            }
#pragma unroll
            for (int i = 0; i < 4; i++)
#pragma unroll
                for (int j = 0; j < 4; j++)
                    acc[i][j] = __builtin_amdgcn_mfma_f32_16x16x32_bf16(a[i], b[j], acc[i][j], 0, 0, 0);
        }
        __syncthreads();
    }
    // epilogue: C/D map col=lane&15, row=(lane>>4)*4+r  -> bf16 store
    const int col_l = lane & 15, rq = lane >> 4;
#pragma unroll
    for (int i = 0; i < 4; i++)
#pragma unroll
        for (int j = 0; j < 4; j++) {
            int e = e0 + wn * 64 + j * 16 + col_l;
#pragma unroll
            for (int r = 0; r < 4; r++) {
                int m = wm * 64 + i * 16 + rq * 4 + r;
                outp[(size_t)m * (NPOS * E_) + n * E_ + e] = f2bf(acc[i][j][r]);
            }
        }
}

// ---------------- Kernel 2: attention per (b,h) -- MFMA version ----------------
// 4 waves; wave w owns q-rows [w*16, w*16+16).
// QK^T: A-frag = Q rows (direct global, row-major bf16), B-frag = K rows
// (K^T[d][j] in B[k][n] layout == K row-major). Softmax fully in-register
// (shfl_xor over the 16 lanes sharing a row). V transposed once into
// swizzled LDS (reg 4x4 micro-transpose). P kept as bf16 hi+lo pair and
// accumulated with two MFMAs -> effectively fp32 P like the old VALU path.
__global__ __launch_bounds__(256) void attn_kernel(
    const unsigned short* __restrict__ qp, const unsigned short* __restrict__ kp,
    const unsigned short* __restrict__ vp,
    float* __restrict__ attn_out,            // [B][H][64][64] fp32
    unsigned short* __restrict__ out_ws) {   // bf16 [B][64][H*DH]
    const int bid = blockIdx.x;
    const int b = bid >> 4, h = bid & 15;
    __shared__ __attribute__((aligned(16))) unsigned short Vt[64 * 72];      // V^T [d][j] swizzled
    __shared__ __attribute__((aligned(16))) unsigned short P2[2][64 * 72];   // P hi/lo [q][j]
    const int t = threadIdx.x;
    const int lane = t & 63, w = t >> 6;
    const int lr = lane & 15, lg = lane >> 4;
    const size_t base = (size_t)b * (64 * E_) + h * DH;

    // ---- stage V^T: each thread transposes one 4x4 block ----
    const int d0 = (t & 15) * 4, j0 = (t >> 4) * 4;
    union U2 { uint2 u; unsigned short s[4]; };
    U2 L0, L1, L2, L3;
    L0.u = *(const uint2*)(vp + base + (size_t)(j0 + 0) * E_ + d0);
    L1.u = *(const uint2*)(vp + base + (size_t)(j0 + 1) * E_ + d0);
    L2.u = *(const uint2*)(vp + base + (size_t)(j0 + 2) * E_ + d0);
    L3.u = *(const uint2*)(vp + base + (size_t)(j0 + 3) * E_ + d0);

    // ---- load Q/K fragments straight from global (16B, 64B/row coalesced) ----
    bf16x8 aq[2], bk[4][2];
#pragma unroll
    for (int ks = 0; ks < 2; ks++)
        aq[ks] = *(const bf16x8*)(qp + base + (size_t)(w * 16 + lr) * E_ + ks * 32 + lg * 8);
#pragma unroll
    for (int jt = 0; jt < 4; jt++)
#pragma unroll
        for (int ks = 0; ks < 2; ks++)
            bk[jt][ks] = *(const bf16x8*)(kp + base + (size_t)(jt * 16 + lr) * E_ + ks * 32 + lg * 8);

    // V^T stores (swizzled, conflict-free uniform over bank pairs)
#pragma unroll
    for (int x = 0; x < 4; x++) {
        U2 S; S.s[0] = L0.s[x]; S.s[1] = L1.s[x]; S.s[2] = L2.s[x]; S.s[3] = L3.s[x];
        int row = d0 + x;
        *(uint2*)((char*)Vt + row * 144 + ((j0 * 2) ^ (((row >> 3) & 7) << 4))) = S.u;
    }

    // ---- QK^T ----
    f32x4 s4[4];
#pragma unroll
    for (int jt = 0; jt < 4; jt++) s4[jt] = (f32x4){0.f, 0.f, 0.f, 0.f};
#pragma unroll
    for (int jt = 0; jt < 4; jt++)
#pragma unroll
        for (int ks = 0; ks < 2; ks++)
            s4[jt] = __builtin_amdgcn_mfma_f32_16x16x32_bf16(aq[ks], bk[jt][ks], s4[jt], 0, 0, 0);

    // ---- softmax in registers; row q = w*16 + lg*4 + r lives in 16 lanes x 4 jt ----
    float p[4][4];   // [jt][r]
#pragma unroll
    for (int jt = 0; jt < 4; jt++)
#pragma unroll
        for (int r = 0; r < 4; r++) p[jt][r] = s4[jt][r] * 0.125f;   // 1/sqrt(64)

#pragma unroll
    for (int r = 0; r < 4; r++) {
        float m = fmaxf(fmaxf(p[0][r], p[1][r]), fmaxf(p[2][r], p[3][r]));
#pragma unroll
        for (int msk = 1; msk < 16; msk <<= 1) m = fmaxf(m, __shfl_xor(m, msk));
        float e0 = __expf(p[0][r] - m), e1 = __expf(p[1][r] - m);
        float e2 = __expf(p[2][r] - m), e3 = __expf(p[3][r] - m);
        float sum = (e0 + e1) + (e2 + e3);
#pragma unroll
        for (int msk = 1; msk < 16; msk <<= 1) sum += __shfl_xor(sum, msk);
        float inv = 1.f / sum;
        p[0][r] = e0 * inv; p[1][r] = e1 * inv; p[2][r] = e2 * inv; p[3][r] = e3 * inv;
    }

    // ---- write attn (fp32) + stage P hi/lo bf16 to LDS ----
    float* abase = attn_out + (size_t)bid * 4096;
#pragma unroll
    for (int jt = 0; jt < 4; jt++)
#pragma unroll
        for (int r = 0; r < 4; r++) {
            int q = w * 16 + lg * 4 + r;
            abase[q * 64 + jt * 16 + lr] = p[jt][r];
            unsigned short hs = f2bf(p[jt][r]);
            float lo = p[jt][r] - bf2f(hs);
            P2[0][q * 72 + jt * 16 + lr] = hs;
            P2[1][q * 72 + jt * 16 + lr] = f2bf(lo);
        }
    __syncthreads();

    // ---- PV: O = P_hi*V + P_lo*V ----
    bf16x8 bv[4][2];
#pragma unroll
    for (int dt = 0; dt < 4; dt++)
#pragma unroll
        for (int ks = 0; ks < 2; ks++) {
            int row = dt * 16 + lr;
            bv[dt][ks] = *(const bf16x8*)((const char*)Vt + row * 144 +
                                          ((ks * 64 + lg * 16) ^ (((row >> 3) & 7) << 4)));
        }
    bf16x8 ah[2], al[2];
#pragma unroll
    for (int ks = 0; ks < 2; ks++) {
        ah[ks] = *(const bf16x8*)&P2[0][(w * 16 + lr) * 72 + ks * 32 + lg * 8];
        al[ks] = *(const bf16x8*)&P2[1][(w * 16 + lr) * 72 + ks * 32 + lg * 8];
    }
    f32x4 o4[4];
#pragma unroll
    for (int dt = 0; dt < 4; dt++) o4[dt] = (f32x4){0.f, 0.f, 0.f, 0.f};
#pragma unroll
    for (int dt = 0; dt < 4; dt++)
#pragma unroll
        for (int ks = 0; ks < 2; ks++) {
            o4[dt] = __builtin_amdgcn_mfma_f32_16x16x32_bf16(ah[ks], bv[dt][ks], o4[dt], 0, 0, 0);
            o4[dt] = __builtin_amdgcn_mfma_f32_16x16x32_bf16(al[ks], bv[dt][ks], o4[dt], 0, 0, 0);
        }

    // ---- epilogue: O rows q = w*16+lg*4+r, cols d = dt*16+lr ----
#pragma unroll
    for (int dt = 0; dt < 4; dt++)
#pragma unroll
        for (int r = 0; r < 4; r++) {
            int q = w * 16 + lg * 4 + r;
            out_ws[(size_t)(b * 64 + q) * E_ + h * DH + dt * 16 + lr] = f2bf(o4[dt][r]);
        }
}

// ---------------- Kernel 3: fused fc + gate + activation ----------------
// C_fc[m,n] = sum_k out[m,k]*fc_w[n,k] ; C_g likewise ; out = sigmoid(g+gb)*tanh(f+fb)
__global__ __launch_bounds__(256, 2) void fcgate_kernel(
    const unsigned short* __restrict__ a,   // bf16 [8192][1024]
    const float* __restrict__ fcw, const float* __restrict__ fcb,
    const float* __restrict__ gw,  const float* __restrict__ gb,
    float* __restrict__ outp) {             // fp32 [8192][1024]
    const int n0 = blockIdx.x * 128;
    const int m0 = blockIdx.y * 128;
    __shared__ __attribute__((aligned(16))) unsigned short As[128 * 72];
    __shared__ __attribute__((aligned(16))) unsigned short Bf[128 * 72];
    __shared__ __attribute__((aligned(16))) unsigned short Bg[128 * 72];
    const int t = threadIdx.x;
    const int lane = t & 63, wave = t >> 6;
    const int wm = wave >> 1, wn = wave & 1;

    f32x4 accf[4][4], accg[4][4];
#pragma unroll
    for (int i = 0; i < 4; i++)
#pragma unroll
        for (int j = 0; j < 4; j++) {
            accf[i][j] = (f32x4){0.f, 0.f, 0.f, 0.f};
            accg[i][j] = (f32x4){0.f, 0.f, 0.f, 0.f};
        }

    const int afr = t & 7,  ar0 = t >> 3;   // A: 8 x 16B chunks per row
    const int bfr = t & 15, br0 = t >> 4;   // B: 16 x float4 per row

    for (int kb = 0; kb < 1024; kb += 64) {
#pragma unroll
        for (int p = 0; p < 4; p++) {
            int row = ar0 + p * 32;
            *(uint4*)&As[row * 72 + afr * 8] =
                *(const uint4*)(a + (size_t)(m0 + row) * 1024 + kb + afr * 8);
        }
#pragma unroll
        for (int p = 0; p < 8; p++) {
            int row = br0 + p * 16;
            F4 cf; cf.v = *(const float4*)(fcw + (size_t)(n0 + row) * 1024 + kb + bfr * 4);
            uint2 pkf; pkf.x = pk2bf(cf.f[0], cf.f[1]); pkf.y = pk2bf(cf.f[2], cf.f[3]);
            *(uint2*)&Bf[row * 72 + bfr * 4] = pkf;
            F4 cg; cg.v = *(const float4*)(gw + (size_t)(n0 + row) * 1024 + kb + bfr * 4);
            uint2 pkg; pkg.x = pk2bf(cg.f[0], cg.f[1]); pkg.y = pk2bf(cg.f[2], cg.f[3]);
            *(uint2*)&Bg[row * 72 + bfr * 4] = pkg;
        }
        __syncthreads();
#pragma unroll
        for (int ks = 0; ks < 64; ks += 32) {
            bf16x8 av[4], bfv[4], bgv[4];
            const int koff = ks + (lane >> 4) * 8;
#pragma unroll
            for (int i = 0; i < 4; i++)
                av[i] = *(const bf16x8*)&As[(wm * 64 + i * 16 + (lane & 15)) * 72 + koff];
#pragma unroll
            for (int j = 0; j < 4; j++) {
                bfv[j] = *(const bf16x8*)&Bf[(wn * 64 + j * 16 + (lane & 15)) * 72 + koff];
                bgv[j] = *(const bf16x8*)&Bg[(wn * 64 + j * 16 + (lane & 15)) * 72 + koff];
            }
#pragma unroll
            for (int i = 0; i < 4; i++)
#pragma unroll
                for (int j = 0; j < 4; j++) {
                    accf[i][j] = __builtin_amdgcn_mfma_f32_16x16x32_bf16(av[i], bfv[j], accf[i][j], 0, 0, 0);
                    accg[i][j] = __builtin_amdgcn_mfma_f32_16x16x32_bf16(av[i], bgv[j], accg[i][j], 0, 0, 0);
                }
        }
        __syncthreads();
    }
    const int col_l = lane & 15, rq = lane >> 4;
#pragma unroll
    for (int i = 0; i < 4; i++)
#pragma unroll
        for (int j = 0; j < 4; j++) {
            int col = n0 + wn * 64 + j * 16 + col_l;
            float bfb = fcb[col], bgb = gb[col];
#pragma unroll
            for (int r = 0; r < 4; r++) {
                int m = m0 + wm * 64 + i * 16 + rq * 4 + r;
                float f = accf[i][j][r] + bfb;
                float g = accg[i][j][r] + bgb;
                float ef = __expf(2.f * f);
                float th = (ef - 1.f) / (ef + 1.f);      // tanh(f)
                float sg = 1.f / (1.f + __expf(-g));     // sigmoid(g)
                outp[(size_t)m * 1024 + col] = sg * th;
            }
        }
}

extern "C" void kernel_launch(void* const* d_in, const int* in_sizes, int n_in,
                              void* d_out, int out_size, void* d_ws, size_t ws_size,
                              hipStream_t stream) {
    const float* q      = (const float*)d_in[0];
    const float* k      = (const float*)d_in[1];
    const float* v      = (const float*)d_in[2];
    const float* w_q    = (const float*)d_in[3];
    const float* w_k    = (const float*)d_in[4];
    const float* w_v    = (const float*)d_in[5];
    const float* fc_w   = (const float*)d_in[6];
    const float* fc_b   = (const float*)d_in[7];
    const float* gate_w = (const float*)d_in[8];
    const float* gate_b = (const float*)d_in[9];

    float* out  = (float*)d_out;              // [128*64][1024]
    float* attn = out + 8388608;              // [128][16][64][64]

    unsigned short* qp  = (unsigned short*)d_ws;   // bf16 [128][64][1024] each
    unsigned short* kp  = qp + 8388608;
    unsigned short* vp  = kp + 8388608;
    unsigned short* ows = vp + 8388608;            // bf16 [8192][1024]

    dim3 blk(256);
    proj_kernel<<<dim3(8, 64, 3), blk, 0, stream>>>(q, k, v, w_q, w_k, w_v, qp, kp, vp);
    attn_kernel<<<dim3(2048), blk, 0, stream>>>(qp, kp, vp, attn, ows);
    fcgate_kernel<<<dim3(8, 64), blk, 0, stream>>>(ows, fc_w, fc_b, gate_w, gate_b, out);
}